// Round 1
// 4258.067 us; speedup vs baseline: 1.0326x; 1.0326x over previous
//
#include <hip/hip_runtime.h>
#include <hip/hip_fp16.h>
#include <math.h>

typedef _Float16 h2 __attribute__((ext_vector_type(2)));
typedef _Float16 h8 __attribute__((ext_vector_type(8)));
typedef float    f4 __attribute__((ext_vector_type(4)));
typedef unsigned short     u16;
typedef unsigned int       u32;
typedef unsigned long long u64;

#define BB 64
#define TT 512
#define DD 256
#define UU 512

#define NBLK 64
#define CPB  44   // packed gate-cols per block: 8*{fs,fl,al,o,WCh} + 4 m
#define XPB  36   // of those, cols with an x-contribution (32 gate + 4 m)
#define UPB  8    // h/c columns owned per block
#define MPB  4    // m (x-dim) columns owned per block
#define NJ   2816
#define NJX  2304

// ---------- ws layout (bytes) ----------
#define OFF_W1   0ull                              // f16 [2816][512] packed, K-contig
#define OFF_W2   (OFF_W1 + 2816ull*512*2)          // f16 [512][256]
#define OFF_WX   (OFF_W2 + 512ull*256*2)           // f16 [2304][256] packed
#define OFF_B1   (OFF_WX + 2304ull*256*2)          // f32 [2816] packed
#define OFF_HB   (OFF_B1 + 2816ull*4)              // f16 [64][512]  h state
#define OFF_MX   (OFF_HB + 64ull*512*2)            // f16 [64][256]  mod_x
#define OFF_CTR  (OFF_MX + 64ull*256*2)            // u32 [1025*16] flags (1 line/block)
#define OFF_XPRE (OFF_CTR + 16400ull*4)            // f16 [512][2304][64]
#define WS_FULL  (OFF_XPRE + 512ull*2304*64*2)     // ~155.5 MB

__device__ __forceinline__ float sigf(float v)     { return 1.0f / (1.0f + __expf(-v)); }
__device__ __forceinline__ float tanhfast(float v) { return 1.0f - 2.0f / (__expf(2.0f * v) + 1.0f); }

// Executed by ONE full wave. Lane i polls flag line i (64B apart). Detection
// is a single parallel load round instead of waiting behind 64 serialized
// RMWs on one line. ONE acquire load at the end emits the single buffer_inv
// (L1+XCD-L2) that makes producers' LLC-resident data visible to this
// block's cached loads.
__device__ __forceinline__ void waitflags_wave(u32* base, u32 tgt, int lane) {
    u32 it = 0;
    for (;;) {
        u32 v = __hip_atomic_load(base + lane * 16, __ATOMIC_RELAXED, __HIP_MEMORY_SCOPE_AGENT);
        if (__ballot(v >= tgt) == ~0ull) break;    // all 64 producer blocks ready
        __builtin_amdgcn_s_sleep(1);
        if (++it > 2000000u) break;   // safety valve (no hard hang)
    }
    (void)__hip_atomic_load(base + lane * 16, __ATOMIC_ACQUIRE, __HIP_MEMORY_SCOPE_AGENT);  // buffer_inv
}

// packed-order helpers (fallback path)
__device__ __forceinline__ int pk5(int g, int u) { return (u >> 3) * 44 + g * 8 + (u & 7); }
__device__ __forceinline__ int pkm(int d)        { return (d >> 2) * 44 + 40 + (d & 3); }

// =====================================================================
// Kernel 1: repack weights into packed block-sliced f16 layouts + zero flags
// =====================================================================
__global__ void repack_kernel(const float* __restrict__ Wfs, const float* __restrict__ Wfl,
                              const float* __restrict__ Wal, const float* __restrict__ Wm,
                              const float* __restrict__ WC,  const float* __restrict__ Wo,
                              const float* __restrict__ bfs, const float* __restrict__ bfl,
                              const float* __restrict__ bal, const float* __restrict__ bm,
                              const float* __restrict__ bC,  const float* __restrict__ bo,
                              _Float16* __restrict__ W1, _Float16* __restrict__ W2,
                              _Float16* __restrict__ WxT, float* __restrict__ b1,
                              u32* __restrict__ ctr)
{
    const int stride = gridDim.x * blockDim.x;
    const int idx = blockIdx.x * blockDim.x + threadIdx.x;

    for (int i = idx; i < 2816 * 512; i += stride) {
        int J = i >> 9, k = i & 511;
        int blk = J / 44, c = J - blk * 44;
        float v;
        if (c < 40) {
            int grp = c >> 3, u = blk * 8 + (c & 7);
            const float* Wg = (grp == 0) ? Wfs : (grp == 1) ? Wfl : (grp == 2) ? Wal : (grp == 3) ? Wo : WC;
            v = Wg[(size_t)k * 512 + u];
        } else {
            int d = blk * 4 + (c - 40);
            v = Wm[(size_t)k * 256 + d];
        }
        W1[i] = (_Float16)v;
    }
    for (int i = idx; i < 512 * 256; i += stride) {
        int u = i >> 8, dd = i & 255;
        W2[i] = (_Float16)WC[(size_t)(512 + dd) * 512 + u];
    }
    for (int i = idx; i < 2304 * 256; i += stride) {
        int Jx = i >> 8, k2 = i & 255;
        int blk = Jx / 36, lc = Jx - blk * 36;
        float v;
        if (lc < 32) {
            int grp = lc >> 3, u = blk * 8 + (lc & 7);
            const float* Wg = (grp == 0) ? Wfs : (grp == 1) ? Wfl : (grp == 2) ? Wal : Wo;
            v = Wg[(size_t)(512 + k2) * 512 + u];
        } else {
            int d = blk * 4 + (lc - 32);
            v = Wm[(size_t)(512 + k2) * 256 + d];
        }
        WxT[i] = (_Float16)v;
    }
    for (int J = idx; J < 2816; J += stride) {
        int blk = J / 44, c = J - blk * 44;
        float v;
        if (c < 40) {
            int grp = c >> 3, u = blk * 8 + (c & 7);
            v = (grp == 0) ? bfs[u] : (grp == 1) ? bfl[u] : (grp == 2) ? bal[u] : (grp == 3) ? bo[u] : bC[u];
        } else {
            v = bm[blk * 4 + (c - 40)];
        }
        b1[J] = v;
    }
    for (int i = idx; i < 16400; i += stride) ctr[i] = 0;
}

// =====================================================================
// Kernel 2: Xpre = x @ W_x via MFMA.  [32768,256]@[256,2304] -> f16
// output layout [t][Jx][b].
// =====================================================================
__global__ __launch_bounds__(256) void xpre_kernel(const float* __restrict__ x,
                                                   const _Float16* __restrict__ WxT,
                                                   _Float16* __restrict__ Xpre)
{
    __shared__ _Float16 As[128 * 32];
    __shared__ _Float16 Bs[128 * 32];

    const int tid  = threadIdx.x;
    const int lane = tid & 63;
    const int w    = tid >> 6;
    const int wm   = w >> 1, wn = w & 1;
    const int quad = lane >> 4, l16 = lane & 15;
    const int row0 = blockIdx.x * 128;
    const int n0   = blockIdx.y * 128;

    f4 acc[4][4];
    for (int i = 0; i < 4; ++i)
        for (int j = 0; j < 4; ++j)
            acc[i][j] = (f4){0.f, 0.f, 0.f, 0.f};

    for (int kt = 0; kt < 8; ++kt) {
        const int k0 = kt * 32;
        {
            int r  = tid >> 3;
            int cg = (tid & 7) * 4;
            for (int rr = r; rr < 128; rr += 32) {
                f4 v = *(const f4*)&x[(size_t)(row0 + rr) * 256 + k0 + cg];
                As[rr * 32 + cg + 0] = (_Float16)v.x;
                As[rr * 32 + cg + 1] = (_Float16)v.y;
                As[rr * 32 + cg + 2] = (_Float16)v.z;
                As[rr * 32 + cg + 3] = (_Float16)v.w;
            }
        }
        {
            int r   = tid & 127;
            int seg = (tid >> 7) * 16;
            const _Float16* src = &WxT[(size_t)(n0 + r) * 256 + k0 + seg];
            *(f4*)&Bs[r * 32 + seg]     = *(const f4*)src;
            *(f4*)&Bs[r * 32 + seg + 8] = *(const f4*)(src + 8);
        }
        __syncthreads();

        h8 af[4], bf[4];
#pragma unroll
        for (int f = 0; f < 4; ++f) {
            af[f] = *(const h8*)&As[(wm * 64 + f * 16 + l16) * 32 + quad * 8];
            bf[f] = *(const h8*)&Bs[(wn * 64 + f * 16 + l16) * 32 + quad * 8];
        }
#pragma unroll
        for (int fm = 0; fm < 4; ++fm)
#pragma unroll
            for (int fn = 0; fn < 4; ++fn)
                acc[fm][fn] = __builtin_amdgcn_mfma_f32_16x16x32_f16(af[fm], bf[fn], acc[fm][fn], 0, 0, 0);
        __syncthreads();
    }

#pragma unroll
    for (int fm = 0; fm < 4; ++fm)
#pragma unroll
        for (int fn = 0; fn < 4; ++fn)
#pragma unroll
            for (int r = 0; r < 4; ++r) {
                int rr = row0 + wm * 64 + fm * 16 + quad * 4 + r;  // x row = b*T+t
                int J  = n0 + wn * 64 + fn * 16 + l16;
                int b = rr >> 9, tt = rr & 511;
                Xpre[((size_t)tt * NJX + J) * 64 + b] = (_Float16)acc[fm][fn][r];
            }
}

// =====================================================================
// Kernel 3: cooperative recurrent scan. 64 blocks x 256 thr. Per step:
//   wave0 ballot-polls 64 per-block h flags -> single inv -> bf regs from
//   LLC -> acc2 -> quad2 lanes hold m pre-acts in REGISTERS (C-layout
//   m=quad*4+r -> packed cols 40..43): mod_x computed + published directly,
//   no LDS bounce, no barrier -> acc0/acc1 (stores drain underneath) ->
//   per-wave mx flag fire -> elementwise -> ballot-poll mx flags -> GEMM2
//   from L2 -> update -> publish h, fire h flag (plain store), out store
//   AFTER the fire so the HBM ack is off the critical path.
// =====================================================================
__global__ __launch_bounds__(256, 1) void rnn_coop(
    const float* __restrict__ x, const float* __restrict__ h0, const float* __restrict__ c0,
    const _Float16* __restrict__ W1, const _Float16* __restrict__ W2,
    const float* __restrict__ b1, const _Float16* __restrict__ Xpre,
    _Float16* __restrict__ hbuf, _Float16* __restrict__ mxbuf, u32* __restrict__ ctr,
    float* __restrict__ out)
{
    __shared__ __align__(16) _Float16 sW1[48 * 512];  // 48 KB, resident all steps
    __shared__ float sS[48 * 68];                     // stride 68: 2-way max (free)
    __shared__ float sF[8 * 64];
    __shared__ float sO[8 * 64];
    __shared__ float sCP[8 * 64];
    __shared__ float sC[8 * 64];
    __shared__ float sB1[44];

    const int tid  = threadIdx.x;
    const int blk  = blockIdx.x;
    const int lane = tid & 63;
    const int w    = tid >> 6;
    const int l16  = lane & 15;
    const int quad = lane >> 4;
    const int swz  = l16 & 7;
    const int br   = w * 16 + l16;   // batch row owned in MFMA B-frags

    u32* hflag  = ctr;               // [64] lines: hflag[i*16]  holds step+1
    u32* mxflag = ctr + 1024;        // [64] lines: mxflag[i*16] counts 4 per step

    // ---- stage W1 slice (44 rows + 4 zero-pad) with chunk swizzle ----
    for (int idx = tid; idx < 48 * 64; idx += 256) {
        int r = idx >> 6, j = idx & 63;
        h8 v = {};
        if (r < CPB) v = *(const h8*)(W1 + ((size_t)(blk * CPB + r) * 512 + j * 8));
        *(h8*)&sW1[(r * 64 + (j ^ (r & 7))) * 8] = v;
    }
    // ---- W2 A-frags in registers for all steps (rows u<8, pad to 16) ----
    h8 af2[8];
#pragma unroll
    for (int ks = 0; ks < 8; ++ks) {
        af2[ks] = (h8){};
        if (l16 < 8)
            af2[ks] = *(const h8*)(W2 + (size_t)(blk * UPB + l16) * 256 + ks * 32 + quad * 8);
    }
    if (tid < CPB) sB1[tid] = b1[blk * CPB + tid];
    // ---- init c (block-local) ----
    for (int idx = tid; idx < UPB * 64; idx += 256) {
        int u = idx >> 6, b = idx & 63;
        sC[u * 64 + b] = c0[b * UU + blk * UPB + u];
    }
    // ---- publish our h0 slice straight to LLC (atomic stores) ----
    if (tid < 128) {
        int q = tid >> 6, b = tid & 63;
        _Float16 hp[4];
#pragma unroll
        for (int r = 0; r < 4; ++r) hp[r] = (_Float16)h0[b * UU + blk * UPB + q * 4 + r];
        u64 hq; __builtin_memcpy(&hq, hp, 8);
        __hip_atomic_store((u64*)(hbuf + (size_t)b * 512 + blk * UPB + q * 4), hq,
                           __ATOMIC_RELAXED, __HIP_MEMORY_SCOPE_AGENT);
    }
    __syncthreads();                      // drains vmcnt: h0 slice at LLC
    if (tid == 0)
        __hip_atomic_store(&hflag[blk * 16], 1u, __ATOMIC_RELAXED, __HIP_MEMORY_SCOPE_AGENT);

    for (int t = 0; t < TT; ++t) {
        // ---- prefetch read-only operands (overlap the h wait) ----
        const _Float16* xp = Xpre + ((size_t)t * NJX + blk * XPB) * 64;
        float pfs[2], pfl[2], pal[2], pov[2];
#pragma unroll
        for (int i = 0; i < 2; ++i) {
            int u = w * 2 + i;
            pfs[i] = (float)xp[(size_t)u * 64 + lane];
            pfl[i] = (float)xp[(size_t)(8 + u) * 64 + lane];
            pal[i] = (float)xp[(size_t)(16 + u) * 64 + lane];
            pov[i] = (float)xp[(size_t)(24 + u) * 64 + lane];
        }
        float pxm[4] = {0.f, 0.f, 0.f, 0.f};
        f4 pxv = {0.f, 0.f, 0.f, 0.f};
        if (quad == 2) {
#pragma unroll
            for (int r = 0; r < 4; ++r)
                pxm[r] = (float)xp[(size_t)(32 + r) * 64 + br];
            pxv = *(const f4*)&x[((size_t)br * TT + t) * DD + blk * MPB];
        }

        // ---- wait for h[t-1] from all blocks (wave0 ballot poll + inv) ----
        if (w == 0) waitflags_wave(hflag, (u32)(t + 1), lane);
        __syncthreads();

        // ---- B-frags: h[b][k] straight from L2 into registers ----
        h8 bf[16];
#pragma unroll
        for (int ks = 0; ks < 16; ++ks)
            bf[ks] = *(const h8*)(hbuf + (size_t)br * 512 + (ks * 4 + quad) * 8);

        // ---- acc2 first: cols 32..47 = WCh(32..39) + m(40..43) ----
        f4 acc2 = {0.f, 0.f, 0.f, 0.f};
#pragma unroll
        for (int ks = 0; ks < 16; ++ks) {
            int jx = (ks * 4 + quad) ^ swz;
            h8 a2 = *(const h8*)&sW1[((32 + l16) * 64 + jx) * 8];
            acc2 = __builtin_amdgcn_mfma_f32_16x16x32_f16(a2, bf[ks], acc2, 0, 0, 0);
        }
        // WCh rows 32..39 to LDS (read at elementwise, after next barrier)
        if (quad < 2) {
#pragma unroll
            for (int r = 0; r < 4; ++r)
                sS[(32 + quad * 4 + r) * 68 + br] = acc2[r];
        }
        // mod_x straight from registers: quad2 lane holds preact[d=blk*4+r][br]
        if (quad == 2) {
            _Float16 mp[4];
#pragma unroll
            for (int r = 0; r < 4; ++r) {
                float mr = acc2[r] + sB1[40 + r] + pxm[r];
                mp[r] = (_Float16)(sigf(mr) * pxv[r]);
            }
            u64 mq; __builtin_memcpy(&mq, mp, 8);
            __hip_atomic_store((u64*)(mxbuf + (size_t)br * 256 + blk * MPB), mq,
                               __ATOMIC_RELAXED, __HIP_MEMORY_SCOPE_AGENT);
        }

        // ---- acc0/acc1: cols 0..31 (fs,fl,al,o), reuse bf regs.
        //      mx stores drain to LLC underneath these 32 MFMAs. ----
        f4 acc0 = {0.f, 0.f, 0.f, 0.f}, acc1 = {0.f, 0.f, 0.f, 0.f};
#pragma unroll
        for (int ks = 0; ks < 16; ++ks) {
            int jx = (ks * 4 + quad) ^ swz;
            h8 a0 = *(const h8*)&sW1[((     l16) * 64 + jx) * 8];
            h8 a1 = *(const h8*)&sW1[((16 + l16) * 64 + jx) * 8];
            acc0 = __builtin_amdgcn_mfma_f32_16x16x32_f16(a0, bf[ks], acc0, 0, 0, 0);
            acc1 = __builtin_amdgcn_mfma_f32_16x16x32_f16(a1, bf[ks], acc1, 0, 0, 0);
        }
        // per-wave fire: own stores已 drained (vmcnt hit 0 during MFMAs)
        asm volatile("s_waitcnt vmcnt(0)" ::: "memory");
        if (quad == 2 && l16 == 0)
            __hip_atomic_fetch_add(&mxflag[blk * 16], 1u, __ATOMIC_RELAXED, __HIP_MEMORY_SCOPE_AGENT);
#pragma unroll
        for (int r = 0; r < 4; ++r) {
            sS[(     quad * 4 + r) * 68 + br] = acc0[r];
            sS[(16 + quad * 4 + r) * 68 + br] = acc1[r];
        }
        __syncthreads();

        // ---- elementwise: f/o gates + cpre ----
#pragma unroll
        for (int i = 0; i < 2; ++i) {
            int u = w * 2 + i;
            float fs = sigf(sS[u * 68 + lane]        + sB1[u]      + pfs[i]);
            float fl = sigf(sS[(8 + u) * 68 + lane]  + sB1[8 + u]  + pfl[i]);
            float al = sigf(sS[(16 + u) * 68 + lane] + sB1[16 + u] + pal[i]);
            sF[u * 64 + lane]  = al * fs + (1.0f - al) * fl;
            sO[u * 64 + lane]  = sigf(sS[(24 + u) * 68 + lane] + sB1[24 + u] + pov[i]);
            sCP[u * 64 + lane] = sS[(32 + u) * 68 + lane] + sB1[32 + u];
        }
        __syncthreads();

        // ---- wait mod_x from all blocks (4 wave-fires per block) ----
        if (w == 0) waitflags_wave(mxflag, 4u * (u32)(t + 1), lane);
        __syncthreads();

        // ---- GEMM2: W2(regs) x mod_x(L2) ; state update; publish h ----
        {
            h8 bf2[8];
#pragma unroll
            for (int ks = 0; ks < 8; ++ks)
                bf2[ks] = *(const h8*)(mxbuf + (size_t)br * 256 + (ks * 4 + quad) * 8);
            f4 aq = {0.f, 0.f, 0.f, 0.f};
#pragma unroll
            for (int ks = 0; ks < 8; ++ks)
                aq = __builtin_amdgcn_mfma_f32_16x16x32_f16(af2[ks], bf2[ks], aq, 0, 0, 0);

            f4 ovec = {0.f, 0.f, 0.f, 0.f};
            const int u0 = quad * 4;
            if (quad < 2) {
                float hv[4];
#pragma unroll
                for (int r = 0; r < 4; ++r) {
                    int u = u0 + r;
                    float ch = tanhfast(aq[r] + sCP[u * 64 + br]);
                    float f  = sF[u * 64 + br];
                    float c  = f * sC[u * 64 + br] + (1.0f - f) * ch;
                    sC[u * 64 + br] = c;
                    hv[r] = sO[u * 64 + br] * tanhfast(c);
                }
                _Float16 hp[4] = {(_Float16)hv[0], (_Float16)hv[1], (_Float16)hv[2], (_Float16)hv[3]};
                u64 hq; __builtin_memcpy(&hq, hp, 8);
                __hip_atomic_store((u64*)(hbuf + (size_t)br * 512 + blk * UPB + u0), hq,
                                   __ATOMIC_RELAXED, __HIP_MEMORY_SCOPE_AGENT);
                ovec = (f4){hv[0], hv[1], hv[2], hv[3]};
            }
            __syncthreads();              // drains vmcnt: h slice at LLC
            if (tid == 0)
                __hip_atomic_store(&hflag[blk * 16], (u32)(t + 2), __ATOMIC_RELAXED, __HIP_MEMORY_SCOPE_AGENT);
            // out store AFTER the fire: HBM ack drains under next h-wait
            if (quad < 2)
                __builtin_nontemporal_store(ovec, (f4*)&out[((size_t)br * TT + t) * UU + blk * UPB + u0]);
        }
    }
}

// =====================================================================
// Fallback (small ws): per-batch dot2 scan on packed weights.
// =====================================================================
__global__ __launch_bounds__(704) void rnn_fb(const float* __restrict__ x,
                                              const float* __restrict__ h0,
                                              const float* __restrict__ c0,
                                              const _Float16* __restrict__ W1,
                                              const _Float16* __restrict__ W2,
                                              const _Float16* __restrict__ WxT,
                                              const float* __restrict__ b1g,
                                              float* __restrict__ out)
{
    __shared__ float g_ld[2816];
    __shared__ float b1_ld[2816];
    __shared__ float h_ld[512];
    __shared__ float x_ld[256];
    __shared__ float f_ld[512];
    __shared__ float o_ld[512];
    __shared__ float c_ld[512];
    __shared__ __align__(16) h2 hx_h2[256];
    __shared__ __align__(16) h2 x16_h2[128];
    __shared__ __align__(16) h2 modx_h2[128];

    const int tid = threadIdx.x;
    const int b   = blockIdx.x;
    const int j0  = tid * 4;
    const int c   = j0 % 44;
    const bool hasx = (c < 32) || (c >= 40);
    const int Jx0 = (j0 / 44) * 36 + (c < 32 ? c : c - 8);

    for (int j = tid; j < 2816; j += 704) b1_ld[j] = b1g[j];
    if (tid < 512) {
        h_ld[tid] = h0[b * 512 + tid];
        c_ld[tid] = c0[b * 512 + tid];
    }
    __syncthreads();

    const f4* __restrict__ w1r = (const f4*)(W1 + (size_t)j0 * 512);
    const float* __restrict__ xrow = x + (size_t)b * TT * DD;
    float* __restrict__ orow = out + (size_t)b * TT * UU;

    for (int t = 0; t < TT; ++t) {
        if (tid < 256) {
            h2 p; p[0] = (_Float16)h_ld[2 * tid]; p[1] = (_Float16)h_ld[2 * tid + 1];
            hx_h2[tid] = p;
        } else if (tid < 384) {
            int i = tid - 256;
            float v0 = xrow[t * DD + 2 * i];
            float v1 = xrow[t * DD + 2 * i + 1];
            x_ld[2 * i] = v0; x_ld[2 * i + 1] = v1;
            h2 p; p[0] = (_Float16)v0; p[1] = (_Float16)v1;
            x16_h2[i] = p;
        }
        __syncthreads();

        float a0 = b1_ld[j0], a1 = b1_ld[j0 + 1], a2 = b1_ld[j0 + 2], a3 = b1_ld[j0 + 3];
        if (hasx) {
            const f4* xr0 = (const f4*)(WxT + (size_t)Jx0 * 256);
            const f4* xr1 = xr0 + 32;
            const f4* xr2 = xr0 + 64;
            const f4* xr3 = xr0 + 96;
            const f4* xv4 = (const f4*)x16_h2;
#pragma unroll 4
            for (int kc = 0; kc < 32; ++kc) {
                f4 xv = xv4[kc];
                f4 w0 = xr0[kc], w1 = xr1[kc], w2 = xr2[kc], w3 = xr3[kc];
                const h2* xpv = (const h2*)&xv;
                const h2* p0 = (const h2*)&w0; const h2* p1 = (const h2*)&w1;
                const h2* p2 = (const h2*)&w2; const h2* p3 = (const h2*)&w3;
#pragma unroll
                for (int u = 0; u < 4; ++u) {
                    a0 = __builtin_amdgcn_fdot2(p0[u], xpv[u], a0, false);
                    a1 = __builtin_amdgcn_fdot2(p1[u], xpv[u], a1, false);
                    a2 = __builtin_amdgcn_fdot2(p2[u], xpv[u], a2, false);
                    a3 = __builtin_amdgcn_fdot2(p3[u], xpv[u], a3, false);
                }
            }
        }
        {
            const f4* hx4 = (const f4*)hx_h2;
            const f4* r0 = w1r;
            const f4* r1 = w1r + 64;
            const f4* r2 = w1r + 128;
            const f4* r3 = w1r + 192;
#pragma unroll 4
            for (int kc = 0; kc < 64; ++kc) {
                f4 hv = hx4[kc];
                f4 w0 = r0[kc], w1 = r1[kc], w2 = r2[kc], w3 = r3[kc];
                const h2* hp = (const h2*)&hv;
                const h2* p0 = (const h2*)&w0; const h2* p1 = (const h2*)&w1;
                const h2* p2 = (const h2*)&w2; const h2* p3 = (const h2*)&w3;
#pragma unroll
                for (int u = 0; u < 4; ++u) {
                    a0 = __builtin_amdgcn_fdot2(p0[u], hp[u], a0, false);
                    a1 = __builtin_amdgcn_fdot2(p1[u], hp[u], a1, false);
                    a2 = __builtin_amdgcn_fdot2(p2[u], hp[u], a2, false);
                    a3 = __builtin_amdgcn_fdot2(p3[u], hp[u], a3, false);
                }
            }
        }
        g_ld[j0] = a0; g_ld[j0 + 1] = a1; g_ld[j0 + 2] = a2; g_ld[j0 + 3] = a3;
        __syncthreads();

        if (tid < 128) {
            float m0 = sigf(g_ld[pkm(2 * tid)]);
            float m1 = sigf(g_ld[pkm(2 * tid + 1)]);
            h2 p;
            p[0] = (_Float16)(m0 * x_ld[2 * tid]);
            p[1] = (_Float16)(m1 * x_ld[2 * tid + 1]);
            modx_h2[tid] = p;
        } else if (tid < 640) {
            int u = tid - 128;
            float fs = sigf(g_ld[pk5(0, u)]);
            float fl = sigf(g_ld[pk5(1, u)]);
            float al = sigf(g_ld[pk5(2, u)]);
            f_ld[u] = al * fs + (1.0f - al) * fl;
            o_ld[u] = sigf(g_ld[pk5(3, u)]);
        }
        __syncthreads();

        if (tid < 512) {
            float s = g_ld[pk5(4, tid)];
            const f4* w2r = (const f4*)(W2 + (size_t)tid * 256);
            const f4* mx4 = (const f4*)modx_h2;
#pragma unroll 4
            for (int kc = 0; kc < 32; ++kc) {
                f4 wv = w2r[kc];
                f4 mv = mx4[kc];
                const h2* wp = (const h2*)&wv;
                const h2* mp = (const h2*)&mv;
#pragma unroll
                for (int u = 0; u < 4; ++u)
                    s = __builtin_amdgcn_fdot2(wp[u], mp[u], s, false);
            }
            float ch = tanhfast(s);
            float f  = f_ld[tid];
            float cc = f * c_ld[tid] + (1.0f - f) * ch;
            c_ld[tid] = cc;
            float h  = o_ld[tid] * tanhfast(cc);
            h_ld[tid] = h;
            orow[t * UU + tid] = h;
        }
        __syncthreads();
    }
}

// =====================================================================
extern "C" void kernel_launch(void* const* d_in, const int* in_sizes, int n_in,
                              void* d_out, int out_size, void* d_ws, size_t ws_size,
                              hipStream_t stream)
{
    (void)in_sizes; (void)n_in; (void)out_size;
    const float* x   = (const float*)d_in[0];
    const float* h0  = (const float*)d_in[1];
    const float* c0  = (const float*)d_in[2];
    const float* Wfs = (const float*)d_in[3];
    const float* bfs = (const float*)d_in[4];
    const float* Wfl = (const float*)d_in[5];
    const float* bfl = (const float*)d_in[6];
    const float* Wal = (const float*)d_in[7];
    const float* bal = (const float*)d_in[8];
    const float* Wm  = (const float*)d_in[9];
    const float* bm  = (const float*)d_in[10];
    const float* WC  = (const float*)d_in[11];
    const float* bC  = (const float*)d_in[12];
    const float* Wo  = (const float*)d_in[13];
    const float* bo  = (const float*)d_in[14];

    char* ws = (char*)d_ws;
    _Float16* W1   = (_Float16*)(ws + OFF_W1);
    _Float16* W2   = (_Float16*)(ws + OFF_W2);
    _Float16* WxT  = (_Float16*)(ws + OFF_WX);
    float*    b1   = (float*)   (ws + OFF_B1);
    _Float16* hbuf = (_Float16*)(ws + OFF_HB);
    _Float16* mxbf = (_Float16*)(ws + OFF_MX);
    u32*      ctr  = (u32*)     (ws + OFF_CTR);
    _Float16* Xpre = (_Float16*)(ws + OFF_XPRE);

    repack_kernel<<<dim3(1024), dim3(256), 0, stream>>>(
        Wfs, Wfl, Wal, Wm, WC, Wo, bfs, bfl, bal, bm, bC, bo, W1, W2, WxT, b1, ctr);

    if (ws_size >= WS_FULL) {
        xpre_kernel<<<dim3(256, 18), dim3(256), 0, stream>>>(x, WxT, Xpre);
        rnn_coop<<<dim3(NBLK), dim3(256), 0, stream>>>(
            x, h0, c0, W1, W2, b1, Xpre, hbuf, mxbf, ctr, (float*)d_out);
    } else {
        rnn_fb<<<dim3(BB), dim3(704), 0, stream>>>(
            x, h0, c0, W1, W2, WxT, b1, (float*)d_out);
    }
}